// Round 8
// baseline (439.807 us; speedup 1.0000x reference)
//
#include <hip/hip_runtime.h>
#include <hip/hip_bf16.h>

#define HW 3136      // 56*56
#define CTOT 64
#define NTOT 128
#define BB 16
#define TTT 8

// ---------- helpers ----------
static __device__ __forceinline__ float bf2f(unsigned short u) {
    union { unsigned int ui; float f; } v;
    v.ui = ((unsigned int)u) << 16;
    return v.f;
}
static __device__ __forceinline__ unsigned short f2bf(float f) {
    union { float f; unsigned int u; } v;
    v.f = f;
    unsigned int u = v.u;
    unsigned int r = (u + 0x7fffu + ((u >> 16) & 1u)) >> 16;  // round-nearest-even
    return (unsigned short)r;
}

// ---------- K0: repack attn weights to [c][dh][kw][head] + zero stats ----------
// grid 9 x 256 = 2304 exact; idx<2048 also zeroes the stats replicas (memset fused).
__global__ void k_repack(const float* __restrict__ aw, float* __restrict__ wpk,
                         float* __restrict__ stats) {
    const int idx = blockIdx.x * 256 + threadIdx.x;  // 2304 exact
    if (idx < 2048) stats[idx] = 0.f;
    if (idx >= 2304) return;
    const int hd = idx & 3;
    const int kw = (idx >> 2) % 3;
    const int dh = (idx / 12) % 3;
    const int c = idx / 36;
    wpk[idx] = aw[hd * 576 + c * 9 + dh * 3 + kw];
}

// ---------- K1: attn = sigmoid(relu(conv2d(x))) FUSED with per-channel stats ----------
// LDS ALIASED: wl (weights, main loop only) and l (reduce scratch, after loop only)
// share one smem[2304] -> LDS 18944->10240 B. With small LDS the CU fits 16 blocks,
// making __launch_bounds__(128,8) ACHIEVABLE so the allocator must target VGPR<=64
// (r7 showed the hint is clamped to the LDS-bound occupancy: 18944B -> 4 waves/EU
// -> hint ignored, VGPR 76, 29% occ, 81us. r1's lucky 64-VGPR compile ran 63.7us.)
// Block 128 = 8 chunks(8ch) x 16 quads; grid = n(128) * tile(49).
__global__ __launch_bounds__(128, 8) void k_attn(const float* __restrict__ x,
                                                 const float* __restrict__ wpk,
                                                 const float* __restrict__ ab,
                                                 float* __restrict__ attn,
                                                 float* __restrict__ stats) {
    const int tile = blockIdx.x % 49;
    const int n = blockIdx.x / 49;
    const int chunk = threadIdx.x >> 4;    // 0..7
    const int qi = threadIdx.x & 15;       // 0..15
    const int quad = tile * 16 + qi;       // 0..783
    const int q = quad % 14;
    const int h = quad / 14;
    const int w0 = q * 4;

    __shared__ float smem[2304];           // phase A: weights wl[2304];
                                           // phase B: reduce scratch l[8][16][17] (2176)
    __shared__ float4 abuf[4][16];         // attn broadcast [head][quad-in-tile]
    float (*l)[16][17] = (float (*)[16][17])smem;

    const float* xn = x + (size_t)n * CTOT * HW;
    const int c0 = chunk * 8;

    // branchless row loader: clamped address + validity mask, address-select edges
    auto loadrows = [&](int c, float r[3][6]) {
#pragma unroll
        for (int dh = 0; dh < 3; ++dh) {
            const int hh = h + dh - 1;
            const bool v = (hh >= 0) && (hh < 56);
            const float* row = xn + c * HW + (v ? hh : h) * 56 + w0;
            const float m = v ? 1.f : 0.f;
            const float4 mid = *(const float4*)row;
            const float e0 = row[(q > 0) ? -1 : 0] * ((q > 0) ? m : 0.f);
            const float e5 = row[(q < 13) ? 4 : 3] * ((q < 13) ? m : 0.f);
            r[dh][0] = e0;
            r[dh][1] = mid.x * m; r[dh][2] = mid.y * m;
            r[dh][3] = mid.z * m; r[dh][4] = mid.w * m;
            r[dh][5] = e5;
        }
    };

    float bufA[3][6], bufB[3][6];
    loadrows(c0, bufA);                    // prologue load in flight during staging

    // stage weights to LDS (2304 floats, 18/thread, coalesced)
#pragma unroll
    for (int i = 0; i < 18; ++i) smem[threadIdx.x + i * 128] = wpk[threadIdx.x + i * 128];
    __syncthreads();

    float acc[4][4];
#pragma unroll
    for (int hd = 0; hd < 4; ++hd)
#pragma unroll
        for (int j = 0; j < 4; ++j) acc[hd][j] = 0.f;

    float midst[8][4];                     // central-row stash for stats

#pragma unroll
    for (int i = 0; i < 8; ++i) {
        float (*cur)[6] = (i & 1) ? bufB : bufA;
        float (*nxt)[6] = (i & 1) ? bufA : bufB;
        if (i < 7) loadrows(c0 + i + 1, nxt);   // prefetch next channel

        midst[i][0] = cur[1][1]; midst[i][1] = cur[1][2];
        midst[i][2] = cur[1][3]; midst[i][3] = cur[1][4];

        const int c = c0 + i;
#pragma unroll
        for (int dh = 0; dh < 3; ++dh) {
            const float* wb = &smem[c * 36 + dh * 12];
            const float4 wk0 = *(const float4*)(wb);
            const float4 wk1 = *(const float4*)(wb + 4);
            const float4 wk2 = *(const float4*)(wb + 8);
#pragma unroll
            for (int j = 0; j < 4; ++j) {
                const float a0 = cur[dh][j], a1 = cur[dh][j + 1], a2 = cur[dh][j + 2];
                acc[0][j] = fmaf(a0, wk0.x, fmaf(a1, wk1.x, fmaf(a2, wk2.x, acc[0][j])));
                acc[1][j] = fmaf(a0, wk0.y, fmaf(a1, wk1.y, fmaf(a2, wk2.y, acc[1][j])));
                acc[2][j] = fmaf(a0, wk0.z, fmaf(a1, wk1.z, fmaf(a2, wk2.z, acc[2][j])));
                acc[3][j] = fmaf(a0, wk0.w, fmaf(a1, wk1.w, fmaf(a2, wk2.w, acc[3][j])));
            }
        }
    }

    // weights dead; re-barrier before overwriting smem with reduce scratch
    __syncthreads();

    // chunk-reduce attn accumulators through LDS
    float* mine = &l[chunk][qi][0];
#pragma unroll
    for (int hd = 0; hd < 4; ++hd)
#pragma unroll
        for (int j = 0; j < 4; ++j) mine[hd * 4 + j] = acc[hd][j];
    __syncthreads();

    if (threadIdx.x < 64) {
        const int hd = threadIdx.x >> 4;
        const int rq = threadIdx.x & 15;
        float s0 = ab[hd], s1 = s0, s2 = s0, s3 = s0;
#pragma unroll
        for (int cch = 0; cch < 8; ++cch) {
            const float* p = &l[cch][rq][hd * 4];
            s0 += p[0]; s1 += p[1]; s2 += p[2]; s3 += p[3];
        }
        float4 o;
        o.x = s0 > 0.f ? 1.f / (1.f + __expf(-s0)) : 0.5f;
        o.y = s1 > 0.f ? 1.f / (1.f + __expf(-s1)) : 0.5f;
        o.z = s2 > 0.f ? 1.f / (1.f + __expf(-s2)) : 0.5f;
        o.w = s3 > 0.f ? 1.f / (1.f + __expf(-s3)) : 0.5f;
        *(float4*)(attn + (size_t)(n * 4 + hd) * HW + (tile * 16 + rq) * 4) = o;
        abuf[hd][rq] = o;
    }
    __syncthreads();

    // ---- fused stats: v = x*attn over this thread's 8 channels x 4 pixels ----
    const int head = chunk >> 1;           // all 8 channels of a thread share one head
    const float4 a4 = abuf[head][qi];
    float s[8], sq[8];
#pragma unroll
    for (int i = 0; i < 8; ++i) {
        const float v0 = midst[i][0] * a4.x;
        const float v1 = midst[i][1] * a4.y;
        const float v2 = midst[i][2] * a4.z;
        const float v3 = midst[i][3] * a4.w;
        s[i] = v0 + v1 + v2 + v3;
        sq[i] = v0 * v0 + v1 * v1 + v2 * v2 + v3 * v3;
    }
    // per-chunk reduce over the 16 qi threads via LDS (reuse l)
#pragma unroll
    for (int i = 0; i < 8; ++i) { mine[i] = s[i]; mine[8 + i] = sq[i]; }
    __syncthreads();
    {
        const int ch2 = threadIdx.x >> 4;  // chunk being reduced
        const int k = threadIdx.x & 15;    // 0..7 = sum, 8..15 = sumsq
        float t = 0.f;
#pragma unroll
        for (int qq = 0; qq < 16; ++qq) t += l[ch2][qq][k];
        const int cc = ch2 * 8 + (k & 7);
        const int rep = blockIdx.x & 15;
        atomicAdd(&stats[rep * 128 + (k >> 3) * 64 + cc], t);
    }
}

// ---------- K4: xbnr = relu(x*attn*scale + shift) -> bf16, attn staged in LDS ----------
// Finalize FOLDED IN: each block computes scale/shift from stats (8 KB, L2-hot)
// redundantly in threads 0..63 -> k_finalize dispatch deleted. Kernel-boundary
// visibility of stats atomics makes this race-free (no device fences).
// Block = (n, spatial slab of 392 px); grid 1024 x 256.
__global__ __launch_bounds__(256) void k_xbnr(const float* __restrict__ x,
                                              const float* __restrict__ attn,
                                              const float* __restrict__ stats,
                                              const float* __restrict__ gamma,
                                              const float* __restrict__ beta,
                                              unsigned short* __restrict__ xbnr) {
    const int s = blockIdx.x & 7;          // spatial slab
    const int n = blockIdx.x >> 3;         // 0..127
    const int base_sp = s * 392;           // pixel offset

    __shared__ float al[4 * 392];          // attn slab [head][392]
    __shared__ float ssl[128];
    for (int i = threadIdx.x; i < 392; i += 256) {   // 98 float4 per head
        const int hd = i / 98;
        const int j = i - hd * 98;
        ((float4*)al)[hd * 98 + j] =
            *(const float4*)(attn + (size_t)(n * 4 + hd) * HW + base_sp + j * 4);
    }
    if (threadIdx.x < 64) {                // inline finalize
        const int c = threadIdx.x;
        float S = 0.f, Q = 0.f;
#pragma unroll
        for (int r = 0; r < 16; ++r) {
            S += stats[r * 128 + c];
            Q += stats[r * 128 + 64 + c];
        }
        const float cnt = 401408.0f;       // 128*3136
        const float mean = S / cnt;
        const float var = Q / cnt - mean * mean;
        const float scale = gamma[c] * rsqrtf(var + 1e-5f);
        ssl[c] = scale;
        ssl[64 + c] = beta[c] - mean * scale;
    }
    __syncthreads();

    for (int wi = threadIdx.x; wi < 6272; wi += 256) {
        const int c = wi / 98;
        const int j = wi - c * 98;
        const float sc = ssl[c], sh = ssl[64 + c];
        const float4 xv = *(const float4*)(x + (size_t)(n * 64 + c) * HW + base_sp + j * 4);
        const float4 av = ((const float4*)al)[(c >> 4) * 98 + j];
        ushort4 o;
        o.x = f2bf(fmaxf(fmaf(xv.x * av.x, sc, sh), 0.f));
        o.y = f2bf(fmaxf(fmaf(xv.y * av.y, sc, sh), 0.f));
        o.z = f2bf(fmaxf(fmaf(xv.z * av.z, sc, sh), 0.f));
        o.w = f2bf(fmaxf(fmaf(xv.w * av.w, sc, sh), 0.f));
        *(ushort4*)(xbnr + (size_t)(n * 64 + c) * HW + base_sp + j * 4) = o;
    }
}

// ---------- K5: grouped conv3d + bias + tanh -> gate (LDS chunk-reduction) ----------
// Round-1 structure + weights staged in LDS (pins codegen: no global loads in loop).
// Block 128 = 8 ic-chunks x 16 quads. Grid = b(16) * oc(2) * tile(49).
__global__ __launch_bounds__(128) void k_conv3d(const unsigned short* __restrict__ xbnr,
                                                const float* __restrict__ w3,
                                                const float* __restrict__ b3,
                                                float* __restrict__ gate) {
    const int tile = blockIdx.x % 49;
    const int oc = (blockIdx.x / 49) & 1;
    const int b = blockIdx.x / 98;
    const int chunk = threadIdx.x >> 4;    // 0..7
    const int qi = threadIdx.x & 15;       // 0..15
    const int quad = tile * 16 + qi;       // 0..783
    const int q = quad % 14;
    const int h = quad / 14;
    const int w0 = q * 4;

    __shared__ float wlds[864];            // this oc's 32 ic x 27 weights
    for (int i = threadIdx.x; i < 864; i += 128) wlds[i] = w3[oc * 864 + i];
    __syncthreads();

    float acc[8][4];
#pragma unroll
    for (int t = 0; t < 8; ++t)
#pragma unroll
        for (int j = 0; j < 4; ++j) acc[t][j] = 0.f;

    const int ic0 = chunk * 4;
    for (int ic = ic0; ic < ic0 + 4; ++ic) {
        const int c = oc * 32 + ic;
        const unsigned short* cbase = xbnr + (size_t)(b * 8 * 64 + c) * HW;
        const float* wic = &wlds[ic * 27];  // (dt, dh, dw)
#pragma unroll
        for (int tt = 0; tt < 8; ++tt) {
            const unsigned short* plane = cbase + (size_t)tt * (64 * HW);
#pragma unroll
            for (int dh = 0; dh < 3; ++dh) {
                const int hh = h + dh - 1;
                if (hh < 0 || hh >= 56) continue;
                const unsigned short* row = plane + hh * 56 + w0;
                const ushort4 mid = *(const ushort4*)row;
                const float f0 = (q > 0) ? bf2f(row[-1]) : 0.f;
                const float f1 = bf2f(mid.x), f2 = bf2f(mid.y);
                const float f3 = bf2f(mid.z), f4 = bf2f(mid.w);
                const float f5 = (q < 13) ? bf2f(row[4]) : 0.f;
#pragma unroll
                for (int dt = 0; dt < 3; ++dt) {
                    const int t = tt + 1 - dt;   // out[t] += in[t+dt-1]*w[dt]
                    if (t < 0 || t > 7) continue;
                    const float* wp = wic + dt * 9 + dh * 3;
                    const float wa = wp[0], wb = wp[1], wc = wp[2];
                    acc[t][0] = fmaf(f0, wa, fmaf(f1, wb, fmaf(f2, wc, acc[t][0])));
                    acc[t][1] = fmaf(f1, wa, fmaf(f2, wb, fmaf(f3, wc, acc[t][1])));
                    acc[t][2] = fmaf(f2, wa, fmaf(f3, wb, fmaf(f4, wc, acc[t][2])));
                    acc[t][3] = fmaf(f3, wa, fmaf(f4, wb, fmaf(f5, wc, acc[t][3])));
                }
            }
        }
    }

    // LDS reduction over chunks. Layout: [chunk][qi][9 float4] (pad 8->9 breaks bank alias)
    __shared__ float4 l4[8 * 16 * 9];
    float4* mine = &l4[(chunk * 16 + qi) * 9];
#pragma unroll
    for (int t = 0; t < 8; ++t) {
        float4 v;
        v.x = acc[t][0]; v.y = acc[t][1]; v.z = acc[t][2]; v.w = acc[t][3];
        mine[t] = v;
    }
    __syncthreads();

    const int rt = threadIdx.x >> 4;   // t of this thread's output
    const int rq = threadIdx.x & 15;   // quad within tile
    float4 s = l4[(0 * 16 + rq) * 9 + rt];
#pragma unroll
    for (int c = 1; c < 8; ++c) {
        const float4 v = l4[(c * 16 + rq) * 9 + rt];
        s.x += v.x; s.y += v.y; s.z += v.z; s.w += v.w;
    }
    const float bb = b3[oc];
    float4 o;
    o.x = tanhf(s.x + bb);
    o.y = tanhf(s.y + bb);
    o.z = tanhf(s.z + bb);
    o.w = tanhf(s.w + bb);
    const int outquad = tile * 16 + rq;
    *(float4*)(gate + (size_t)((b * 2 + oc) * 8 + rt) * HW + outquad * 4) = o;
}

// ---------- K6: final gating + temporal shift + interleave ----------
// Block = (b, h, head-pair): 448 threads = 32 co x 14 q, grid = 16*56*2 = 1792.
// All threads share grp (gate read exactly once) and two heads (attn read once;
// 16 same-address lanes coalesce to one transaction). FETCH ideal ~117 MB.
__global__ __launch_bounds__(448) void k_final(const float* __restrict__ x,
                                               const float* __restrict__ attn,
                                               const float* __restrict__ gate,
                                               float* __restrict__ out) {
    const int hg = blockIdx.x & 1;          // head-pair group == grp
    const int h = (blockIdx.x >> 1) % 56;
    const int b = blockIdx.x / 112;
    const int q = threadIdx.x % 14;
    const int col = threadIdx.x / 14;       // 0..31
    const int co = hg * 32 + col;
    const int sp = h * 56 + q * 4;

    int cs;
    if (co < 32) {
        cs = ((co & 1) << 4) | (co >> 1);
    } else {
        const int cc = co - 32;
        cs = 32 + (((cc & 1) << 4) | (cc >> 1));
    }
    const int grp = hg;
    const int head = cs >> 4;

    float4 x2v[8], g[8];
#pragma unroll
    for (int t = 0; t < 8; ++t) {
        const int n = b * 8 + t;
        const float4 xv = *(const float4*)(x + (size_t)(n * 64 + cs) * HW + sp);
        const float4 av = *(const float4*)(attn + (size_t)(n * 4 + head) * HW + sp);
        const float4 gv = *(const float4*)(gate + (size_t)((b * 2 + grp) * 8 + t) * HW + sp);
        x2v[t].x = xv.x * av.x;
        x2v[t].y = xv.y * av.y;
        x2v[t].z = xv.z * av.z;
        x2v[t].w = xv.w * av.w;
        g[t] = gv;
    }
#pragma unroll
    for (int t = 0; t < 8; ++t) {
        float4 o;
        o.x = x2v[t].x * (1.f - g[t].x);
        o.y = x2v[t].y * (1.f - g[t].y);
        o.z = x2v[t].z * (1.f - g[t].z);
        o.w = x2v[t].w * (1.f - g[t].w);
        if (grp == 0) {
            if (t < 7) {
                o.x += x2v[t + 1].x * g[t + 1].x;
                o.y += x2v[t + 1].y * g[t + 1].y;
                o.z += x2v[t + 1].z * g[t + 1].z;
                o.w += x2v[t + 1].w * g[t + 1].w;
            }
        } else {
            if (t > 0) {
                o.x += x2v[t - 1].x * g[t - 1].x;
                o.y += x2v[t - 1].y * g[t - 1].y;
                o.z += x2v[t - 1].z * g[t - 1].z;
                o.w += x2v[t - 1].w * g[t - 1].w;
            }
        }
        *(float4*)(out + (size_t)((b * 8 + t) * 64 + co) * HW + sp) = o;
    }
}

// ---------- launch ----------
extern "C" void kernel_launch(void* const* d_in, const int* in_sizes, int n_in,
                              void* d_out, int out_size, void* d_ws, size_t ws_size,
                              hipStream_t stream) {
    const float* x = (const float*)d_in[0];
    const float* aw = (const float*)d_in[1];
    const float* ab = (const float*)d_in[2];
    const float* gamma = (const float*)d_in[3];
    const float* beta = (const float*)d_in[4];
    const float* w3 = (const float*)d_in[5];
    const float* b3 = (const float*)d_in[6];
    float* out = (float*)d_out;

    char* ws = (char*)d_ws;
    // layout: xbnr bf16 [0, 51380224) | attn f32 | gate f32 (stats aliases its head,
    // lifetimes disjoint: stats dead before k_conv3d writes gate) | wpk
    unsigned short* xbnr = (unsigned short*)ws;
    float* attn = (float*)(ws + 51380224);            // 128*4*3136 f32 = 6422528 B
    float* gate = (float*)(ws + 57802752);            // 16*2*8*3136 f32 = 3211264 B
    float* stats = (float*)(ws + 57802752);           // 16 reps x 128 f32 = 8192 B (aliases gate)
    float* wpk = (float*)(ws + 61015040);             // 2304 f32

    k_repack<<<9, 256, 0, stream>>>(aw, wpk, stats);  // also zeroes stats
    k_attn<<<6272, 128, 0, stream>>>(x, wpk, ab, attn, stats);
    k_xbnr<<<1024, 256, 0, stream>>>(x, attn, stats, gamma, beta, xbnr);
    k_conv3d<<<1568, 128, 0, stream>>>(xbnr, w3, b3, gate);
    k_final<<<1792, 448, 0, stream>>>(x, attn, gate, out);
}

// Round 9
// 411.789 us; speedup vs baseline: 1.0680x; 1.0680x over previous
//
#include <hip/hip_runtime.h>
#include <hip/hip_bf16.h>

#define HW 3136      // 56*56
#define CTOT 64
#define NTOT 128
#define BB 16
#define TTT 8

// ---------- helpers ----------
static __device__ __forceinline__ float bf2f(unsigned short u) {
    union { unsigned int ui; float f; } v;
    v.ui = ((unsigned int)u) << 16;
    return v.f;
}
static __device__ __forceinline__ unsigned short f2bf(float f) {
    union { float f; unsigned int u; } v;
    v.f = f;
    unsigned int u = v.u;
    unsigned int r = (u + 0x7fffu + ((u >> 16) & 1u)) >> 16;  // round-nearest-even
    return (unsigned short)r;
}

// ---------- K0: repack attn weights to [c][dh][kw][head] + zero stats ----------
// grid 9 x 256 = 2304 exact; idx<2048 also zeroes the stats replicas (memset fused).
__global__ void k_repack(const float* __restrict__ aw, float* __restrict__ wpk,
                         float* __restrict__ stats) {
    const int idx = blockIdx.x * 256 + threadIdx.x;  // 2304 exact
    if (idx < 2048) stats[idx] = 0.f;
    if (idx >= 2304) return;
    const int hd = idx & 3;
    const int kw = (idx >> 2) % 3;
    const int dh = (idx / 12) % 3;
    const int c = idx / 36;
    wpk[idx] = aw[hd * 576 + c * 9 + dh * 3 + kw];
}

// ---------- K1: attn = sigmoid(relu(conv2d(x))) FUSED with per-channel stats ----------
// LDS ALIASED (r8, verified correct): wl and l share smem -> LDS 10240 B, CU fits
// 12+ blocks. __launch_bounds__(128, 6): VGPR cap 512/6=85 >= natural 76 -> bound
// is satisfiable WITHOUT spilling (r8's (128,8) cap 64 forced VGPR 32 + 210 MB of
// scratch spill traffic, 147us; r7's (128,8)+big-LDS was ignored, 82us).
// Block 128 = 8 chunks(8ch) x 16 quads; grid = n(128) * tile(49).
__global__ __launch_bounds__(128, 6) void k_attn(const float* __restrict__ x,
                                                 const float* __restrict__ wpk,
                                                 const float* __restrict__ ab,
                                                 float* __restrict__ attn,
                                                 float* __restrict__ stats) {
    const int tile = blockIdx.x % 49;
    const int n = blockIdx.x / 49;
    const int chunk = threadIdx.x >> 4;    // 0..7
    const int qi = threadIdx.x & 15;       // 0..15
    const int quad = tile * 16 + qi;       // 0..783
    const int q = quad % 14;
    const int h = quad / 14;
    const int w0 = q * 4;

    __shared__ float smem[2304];           // phase A: weights wl[2304];
                                           // phase B: reduce scratch l[8][16][17] (2176)
    __shared__ float4 abuf[4][16];         // attn broadcast [head][quad-in-tile]
    float (*l)[16][17] = (float (*)[16][17])smem;

    const float* xn = x + (size_t)n * CTOT * HW;
    const int c0 = chunk * 8;

    // branchless row loader: clamped address + validity mask, address-select edges
    auto loadrows = [&](int c, float r[3][6]) {
#pragma unroll
        for (int dh = 0; dh < 3; ++dh) {
            const int hh = h + dh - 1;
            const bool v = (hh >= 0) && (hh < 56);
            const float* row = xn + c * HW + (v ? hh : h) * 56 + w0;
            const float m = v ? 1.f : 0.f;
            const float4 mid = *(const float4*)row;
            const float e0 = row[(q > 0) ? -1 : 0] * ((q > 0) ? m : 0.f);
            const float e5 = row[(q < 13) ? 4 : 3] * ((q < 13) ? m : 0.f);
            r[dh][0] = e0;
            r[dh][1] = mid.x * m; r[dh][2] = mid.y * m;
            r[dh][3] = mid.z * m; r[dh][4] = mid.w * m;
            r[dh][5] = e5;
        }
    };

    float bufA[3][6], bufB[3][6];
    loadrows(c0, bufA);                    // prologue load in flight during staging

    // stage weights to LDS (2304 floats, 18/thread, coalesced)
#pragma unroll
    for (int i = 0; i < 18; ++i) smem[threadIdx.x + i * 128] = wpk[threadIdx.x + i * 128];
    __syncthreads();

    float acc[4][4];
#pragma unroll
    for (int hd = 0; hd < 4; ++hd)
#pragma unroll
        for (int j = 0; j < 4; ++j) acc[hd][j] = 0.f;

    float midst[8][4];                     // central-row stash for stats

#pragma unroll
    for (int i = 0; i < 8; ++i) {
        float (*cur)[6] = (i & 1) ? bufB : bufA;
        float (*nxt)[6] = (i & 1) ? bufA : bufB;
        if (i < 7) loadrows(c0 + i + 1, nxt);   // prefetch next channel

        midst[i][0] = cur[1][1]; midst[i][1] = cur[1][2];
        midst[i][2] = cur[1][3]; midst[i][3] = cur[1][4];

        const int c = c0 + i;
#pragma unroll
        for (int dh = 0; dh < 3; ++dh) {
            const float* wb = &smem[c * 36 + dh * 12];
            const float4 wk0 = *(const float4*)(wb);
            const float4 wk1 = *(const float4*)(wb + 4);
            const float4 wk2 = *(const float4*)(wb + 8);
#pragma unroll
            for (int j = 0; j < 4; ++j) {
                const float a0 = cur[dh][j], a1 = cur[dh][j + 1], a2 = cur[dh][j + 2];
                acc[0][j] = fmaf(a0, wk0.x, fmaf(a1, wk1.x, fmaf(a2, wk2.x, acc[0][j])));
                acc[1][j] = fmaf(a0, wk0.y, fmaf(a1, wk1.y, fmaf(a2, wk2.y, acc[1][j])));
                acc[2][j] = fmaf(a0, wk0.z, fmaf(a1, wk1.z, fmaf(a2, wk2.z, acc[2][j])));
                acc[3][j] = fmaf(a0, wk0.w, fmaf(a1, wk1.w, fmaf(a2, wk2.w, acc[3][j])));
            }
        }
    }

    // weights dead; re-barrier before overwriting smem with reduce scratch
    __syncthreads();

    // chunk-reduce attn accumulators through LDS
    float* mine = &l[chunk][qi][0];
#pragma unroll
    for (int hd = 0; hd < 4; ++hd)
#pragma unroll
        for (int j = 0; j < 4; ++j) mine[hd * 4 + j] = acc[hd][j];
    __syncthreads();

    if (threadIdx.x < 64) {
        const int hd = threadIdx.x >> 4;
        const int rq = threadIdx.x & 15;
        float s0 = ab[hd], s1 = s0, s2 = s0, s3 = s0;
#pragma unroll
        for (int cch = 0; cch < 8; ++cch) {
            const float* p = &l[cch][rq][hd * 4];
            s0 += p[0]; s1 += p[1]; s2 += p[2]; s3 += p[3];
        }
        float4 o;
        o.x = s0 > 0.f ? 1.f / (1.f + __expf(-s0)) : 0.5f;
        o.y = s1 > 0.f ? 1.f / (1.f + __expf(-s1)) : 0.5f;
        o.z = s2 > 0.f ? 1.f / (1.f + __expf(-s2)) : 0.5f;
        o.w = s3 > 0.f ? 1.f / (1.f + __expf(-s3)) : 0.5f;
        *(float4*)(attn + (size_t)(n * 4 + hd) * HW + (tile * 16 + rq) * 4) = o;
        abuf[hd][rq] = o;
    }
    __syncthreads();

    // ---- fused stats: v = x*attn over this thread's 8 channels x 4 pixels ----
    const int head = chunk >> 1;           // all 8 channels of a thread share one head
    const float4 a4 = abuf[head][qi];
    float s[8], sq[8];
#pragma unroll
    for (int i = 0; i < 8; ++i) {
        const float v0 = midst[i][0] * a4.x;
        const float v1 = midst[i][1] * a4.y;
        const float v2 = midst[i][2] * a4.z;
        const float v3 = midst[i][3] * a4.w;
        s[i] = v0 + v1 + v2 + v3;
        sq[i] = v0 * v0 + v1 * v1 + v2 * v2 + v3 * v3;
    }
    // per-chunk reduce over the 16 qi threads via LDS (reuse l)
#pragma unroll
    for (int i = 0; i < 8; ++i) { mine[i] = s[i]; mine[8 + i] = sq[i]; }
    __syncthreads();
    {
        const int ch2 = threadIdx.x >> 4;  // chunk being reduced
        const int k = threadIdx.x & 15;    // 0..7 = sum, 8..15 = sumsq
        float t = 0.f;
#pragma unroll
        for (int qq = 0; qq < 16; ++qq) t += l[ch2][qq][k];
        const int cc = ch2 * 8 + (k & 7);
        const int rep = blockIdx.x & 15;
        atomicAdd(&stats[rep * 128 + (k >> 3) * 64 + cc], t);
    }
}

// ---------- K4: xbnr = relu(x*attn*scale + shift) -> bf16, attn staged in LDS ----------
// Finalize FOLDED IN: each block computes scale/shift from stats (8 KB, L2-hot)
// redundantly in threads 0..63 -> k_finalize dispatch deleted. Kernel-boundary
// visibility of stats atomics makes this race-free (no device fences).
// Block = (n, spatial slab of 392 px); grid 1024 x 256.
__global__ __launch_bounds__(256) void k_xbnr(const float* __restrict__ x,
                                              const float* __restrict__ attn,
                                              const float* __restrict__ stats,
                                              const float* __restrict__ gamma,
                                              const float* __restrict__ beta,
                                              unsigned short* __restrict__ xbnr) {
    const int s = blockIdx.x & 7;          // spatial slab
    const int n = blockIdx.x >> 3;         // 0..127
    const int base_sp = s * 392;           // pixel offset

    __shared__ float al[4 * 392];          // attn slab [head][392]
    __shared__ float ssl[128];
    for (int i = threadIdx.x; i < 392; i += 256) {   // 98 float4 per head
        const int hd = i / 98;
        const int j = i - hd * 98;
        ((float4*)al)[hd * 98 + j] =
            *(const float4*)(attn + (size_t)(n * 4 + hd) * HW + base_sp + j * 4);
    }
    if (threadIdx.x < 64) {                // inline finalize
        const int c = threadIdx.x;
        float S = 0.f, Q = 0.f;
#pragma unroll
        for (int r = 0; r < 16; ++r) {
            S += stats[r * 128 + c];
            Q += stats[r * 128 + 64 + c];
        }
        const float cnt = 401408.0f;       // 128*3136
        const float mean = S / cnt;
        const float var = Q / cnt - mean * mean;
        const float scale = gamma[c] * rsqrtf(var + 1e-5f);
        ssl[c] = scale;
        ssl[64 + c] = beta[c] - mean * scale;
    }
    __syncthreads();

    for (int wi = threadIdx.x; wi < 6272; wi += 256) {
        const int c = wi / 98;
        const int j = wi - c * 98;
        const float sc = ssl[c], sh = ssl[64 + c];
        const float4 xv = *(const float4*)(x + (size_t)(n * 64 + c) * HW + base_sp + j * 4);
        const float4 av = ((const float4*)al)[(c >> 4) * 98 + j];
        ushort4 o;
        o.x = f2bf(fmaxf(fmaf(xv.x * av.x, sc, sh), 0.f));
        o.y = f2bf(fmaxf(fmaf(xv.y * av.y, sc, sh), 0.f));
        o.z = f2bf(fmaxf(fmaf(xv.z * av.z, sc, sh), 0.f));
        o.w = f2bf(fmaxf(fmaf(xv.w * av.w, sc, sh), 0.f));
        *(ushort4*)(xbnr + (size_t)(n * 64 + c) * HW + base_sp + j * 4) = o;
    }
}

// ---------- K5: grouped conv3d + bias + tanh -> gate (LDS chunk-reduction) ----------
// Round-1 structure + weights staged in LDS (pins codegen: no global loads in loop).
// Block 128 = 8 ic-chunks x 16 quads. Grid = b(16) * oc(2) * tile(49).
__global__ __launch_bounds__(128) void k_conv3d(const unsigned short* __restrict__ xbnr,
                                                const float* __restrict__ w3,
                                                const float* __restrict__ b3,
                                                float* __restrict__ gate) {
    const int tile = blockIdx.x % 49;
    const int oc = (blockIdx.x / 49) & 1;
    const int b = blockIdx.x / 98;
    const int chunk = threadIdx.x >> 4;    // 0..7
    const int qi = threadIdx.x & 15;       // 0..15
    const int quad = tile * 16 + qi;       // 0..783
    const int q = quad % 14;
    const int h = quad / 14;
    const int w0 = q * 4;

    __shared__ float wlds[864];            // this oc's 32 ic x 27 weights
    for (int i = threadIdx.x; i < 864; i += 128) wlds[i] = w3[oc * 864 + i];
    __syncthreads();

    float acc[8][4];
#pragma unroll
    for (int t = 0; t < 8; ++t)
#pragma unroll
        for (int j = 0; j < 4; ++j) acc[t][j] = 0.f;

    const int ic0 = chunk * 4;
    for (int ic = ic0; ic < ic0 + 4; ++ic) {
        const int c = oc * 32 + ic;
        const unsigned short* cbase = xbnr + (size_t)(b * 8 * 64 + c) * HW;
        const float* wic = &wlds[ic * 27];  // (dt, dh, dw)
#pragma unroll
        for (int tt = 0; tt < 8; ++tt) {
            const unsigned short* plane = cbase + (size_t)tt * (64 * HW);
#pragma unroll
            for (int dh = 0; dh < 3; ++dh) {
                const int hh = h + dh - 1;
                if (hh < 0 || hh >= 56) continue;
                const unsigned short* row = plane + hh * 56 + w0;
                const ushort4 mid = *(const ushort4*)row;
                const float f0 = (q > 0) ? bf2f(row[-1]) : 0.f;
                const float f1 = bf2f(mid.x), f2 = bf2f(mid.y);
                const float f3 = bf2f(mid.z), f4 = bf2f(mid.w);
                const float f5 = (q < 13) ? bf2f(row[4]) : 0.f;
#pragma unroll
                for (int dt = 0; dt < 3; ++dt) {
                    const int t = tt + 1 - dt;   // out[t] += in[t+dt-1]*w[dt]
                    if (t < 0 || t > 7) continue;
                    const float* wp = wic + dt * 9 + dh * 3;
                    const float wa = wp[0], wb = wp[1], wc = wp[2];
                    acc[t][0] = fmaf(f0, wa, fmaf(f1, wb, fmaf(f2, wc, acc[t][0])));
                    acc[t][1] = fmaf(f1, wa, fmaf(f2, wb, fmaf(f3, wc, acc[t][1])));
                    acc[t][2] = fmaf(f2, wa, fmaf(f3, wb, fmaf(f4, wc, acc[t][2])));
                    acc[t][3] = fmaf(f3, wa, fmaf(f4, wb, fmaf(f5, wc, acc[t][3])));
                }
            }
        }
    }

    // LDS reduction over chunks. Layout: [chunk][qi][9 float4] (pad 8->9 breaks bank alias)
    __shared__ float4 l4[8 * 16 * 9];
    float4* mine = &l4[(chunk * 16 + qi) * 9];
#pragma unroll
    for (int t = 0; t < 8; ++t) {
        float4 v;
        v.x = acc[t][0]; v.y = acc[t][1]; v.z = acc[t][2]; v.w = acc[t][3];
        mine[t] = v;
    }
    __syncthreads();

    const int rt = threadIdx.x >> 4;   // t of this thread's output
    const int rq = threadIdx.x & 15;   // quad within tile
    float4 s = l4[(0 * 16 + rq) * 9 + rt];
#pragma unroll
    for (int c = 1; c < 8; ++c) {
        const float4 v = l4[(c * 16 + rq) * 9 + rt];
        s.x += v.x; s.y += v.y; s.z += v.z; s.w += v.w;
    }
    const float bb = b3[oc];
    float4 o;
    o.x = tanhf(s.x + bb);
    o.y = tanhf(s.y + bb);
    o.z = tanhf(s.z + bb);
    o.w = tanhf(s.w + bb);
    const int outquad = tile * 16 + rq;
    *(float4*)(gate + (size_t)((b * 2 + oc) * 8 + rt) * HW + outquad * 4) = o;
}

// ---------- K6: final gating + temporal shift + interleave ----------
// Block = (b, h, head-pair): 448 threads = 32 co x 14 q, grid = 16*56*2 = 1792.
// All threads share grp (gate read exactly once) and two heads (attn read once;
// 16 same-address lanes coalesce to one transaction). FETCH ideal ~117 MB.
__global__ __launch_bounds__(448) void k_final(const float* __restrict__ x,
                                               const float* __restrict__ attn,
                                               const float* __restrict__ gate,
                                               float* __restrict__ out) {
    const int hg = blockIdx.x & 1;          // head-pair group == grp
    const int h = (blockIdx.x >> 1) % 56;
    const int b = blockIdx.x / 112;
    const int q = threadIdx.x % 14;
    const int col = threadIdx.x / 14;       // 0..31
    const int co = hg * 32 + col;
    const int sp = h * 56 + q * 4;

    int cs;
    if (co < 32) {
        cs = ((co & 1) << 4) | (co >> 1);
    } else {
        const int cc = co - 32;
        cs = 32 + (((cc & 1) << 4) | (cc >> 1));
    }
    const int grp = hg;
    const int head = cs >> 4;

    float4 x2v[8], g[8];
#pragma unroll
    for (int t = 0; t < 8; ++t) {
        const int n = b * 8 + t;
        const float4 xv = *(const float4*)(x + (size_t)(n * 64 + cs) * HW + sp);
        const float4 av = *(const float4*)(attn + (size_t)(n * 4 + head) * HW + sp);
        const float4 gv = *(const float4*)(gate + (size_t)((b * 2 + grp) * 8 + t) * HW + sp);
        x2v[t].x = xv.x * av.x;
        x2v[t].y = xv.y * av.y;
        x2v[t].z = xv.z * av.z;
        x2v[t].w = xv.w * av.w;
        g[t] = gv;
    }
#pragma unroll
    for (int t = 0; t < 8; ++t) {
        float4 o;
        o.x = x2v[t].x * (1.f - g[t].x);
        o.y = x2v[t].y * (1.f - g[t].y);
        o.z = x2v[t].z * (1.f - g[t].z);
        o.w = x2v[t].w * (1.f - g[t].w);
        if (grp == 0) {
            if (t < 7) {
                o.x += x2v[t + 1].x * g[t + 1].x;
                o.y += x2v[t + 1].y * g[t + 1].y;
                o.z += x2v[t + 1].z * g[t + 1].z;
                o.w += x2v[t + 1].w * g[t + 1].w;
            }
        } else {
            if (t > 0) {
                o.x += x2v[t - 1].x * g[t - 1].x;
                o.y += x2v[t - 1].y * g[t - 1].y;
                o.z += x2v[t - 1].z * g[t - 1].z;
                o.w += x2v[t - 1].w * g[t - 1].w;
            }
        }
        *(float4*)(out + (size_t)((b * 8 + t) * 64 + co) * HW + sp) = o;
    }
}

// ---------- launch ----------
extern "C" void kernel_launch(void* const* d_in, const int* in_sizes, int n_in,
                              void* d_out, int out_size, void* d_ws, size_t ws_size,
                              hipStream_t stream) {
    const float* x = (const float*)d_in[0];
    const float* aw = (const float*)d_in[1];
    const float* ab = (const float*)d_in[2];
    const float* gamma = (const float*)d_in[3];
    const float* beta = (const float*)d_in[4];
    const float* w3 = (const float*)d_in[5];
    const float* b3 = (const float*)d_in[6];
    float* out = (float*)d_out;

    char* ws = (char*)d_ws;
    // layout: xbnr bf16 [0, 51380224) | attn f32 | gate f32 (stats aliases its head,
    // lifetimes disjoint: stats dead before k_conv3d writes gate) | wpk
    unsigned short* xbnr = (unsigned short*)ws;
    float* attn = (float*)(ws + 51380224);            // 128*4*3136 f32 = 6422528 B
    float* gate = (float*)(ws + 57802752);            // 16*2*8*3136 f32 = 3211264 B
    float* stats = (float*)(ws + 57802752);           // 16 reps x 128 f32 = 8192 B (aliases gate)
    float* wpk = (float*)(ws + 61015040);             // 2304 f32

    k_repack<<<9, 256, 0, stream>>>(aw, wpk, stats);  // also zeroes stats
    k_attn<<<6272, 128, 0, stream>>>(x, wpk, ab, attn, stats);
    k_xbnr<<<1024, 256, 0, stream>>>(x, attn, stats, gamma, beta, xbnr);
    k_conv3d<<<1568, 128, 0, stream>>>(xbnr, w3, b3, gate);
    k_final<<<1792, 448, 0, stream>>>(x, attn, gate, out);
}

// Round 10
// 360.776 us; speedup vs baseline: 1.2191x; 1.1414x over previous
//
#include <hip/hip_runtime.h>
#include <hip/hip_bf16.h>

#define HW 3136      // 56*56
#define CTOT 64
#define NTOT 128
#define BB 16
#define TTT 8

// ---------- helpers ----------
static __device__ __forceinline__ float bf2f(unsigned short u) {
    union { unsigned int ui; float f; } v;
    v.ui = ((unsigned int)u) << 16;
    return v.f;
}
static __device__ __forceinline__ unsigned short f2bf(float f) {
    union { float f; unsigned int u; } v;
    v.f = f;
    unsigned int u = v.u;
    unsigned int r = (u + 0x7fffu + ((u >> 16) & 1u)) >> 16;  // round-nearest-even
    return (unsigned short)r;
}

// ---------- K0: repack attn weights to [c][dh][kw][head] + zero stats ----------
// grid 9 x 256 = 2304 exact; idx<2048 also zeroes the stats replicas (memset fused).
__global__ void k_repack(const float* __restrict__ aw, float* __restrict__ wpk,
                         float* __restrict__ stats) {
    const int idx = blockIdx.x * 256 + threadIdx.x;  // 2304 exact
    if (idx < 2048) stats[idx] = 0.f;
    if (idx >= 2304) return;
    const int hd = idx & 3;
    const int kw = (idx >> 2) % 3;
    const int dh = (idx / 12) % 3;
    const int c = idx / 36;
    wpk[idx] = aw[hd * 576 + c * 9 + dh * 3 + kw];
}

// ---------- K1: attn = sigmoid(relu(conv2d(x))) FUSED with per-channel stats ----------
// Register-pressure reduced STRUCTURALLY: midst[8][4] (32 VGPR live across the whole
// main loop) deleted; stats phase RE-LOADS the 8 central-row float4s (L2-hot, block
// footprint ~50 KB; central row never masked -> bit-identical). No launch_bounds
// waves-hint: r8/r9 proved ANY second arg makes the allocator spill to meet it
// (r8 (128,8): VGPR 32, +210 MB spill traffic; r9 (128,6): VGPR 40, +93 MB).
// LDS aliased (r8-verified): wl/l share smem -> 10240 B.
// Block 128 = 8 chunks(8ch) x 16 quads; grid = n(128) * tile(49).
__global__ __launch_bounds__(128) void k_attn(const float* __restrict__ x,
                                              const float* __restrict__ wpk,
                                              const float* __restrict__ ab,
                                              float* __restrict__ attn,
                                              float* __restrict__ stats) {
    const int tile = blockIdx.x % 49;
    const int n = blockIdx.x / 49;
    const int chunk = threadIdx.x >> 4;    // 0..7
    const int qi = threadIdx.x & 15;       // 0..15
    const int quad = tile * 16 + qi;       // 0..783
    const int q = quad % 14;
    const int h = quad / 14;
    const int w0 = q * 4;

    __shared__ float smem[2304];           // phase A: weights wl[2304];
                                           // phase B: reduce scratch l[8][16][17] (2176)
    __shared__ float4 abuf[4][16];         // attn broadcast [head][quad-in-tile]
    float (*l)[16][17] = (float (*)[16][17])smem;

    const float* xn = x + (size_t)n * CTOT * HW;
    const int c0 = chunk * 8;

    // branchless row loader: clamped address + validity mask, address-select edges
    auto loadrows = [&](int c, float r[3][6]) {
#pragma unroll
        for (int dh = 0; dh < 3; ++dh) {
            const int hh = h + dh - 1;
            const bool v = (hh >= 0) && (hh < 56);
            const float* row = xn + c * HW + (v ? hh : h) * 56 + w0;
            const float m = v ? 1.f : 0.f;
            const float4 mid = *(const float4*)row;
            const float e0 = row[(q > 0) ? -1 : 0] * ((q > 0) ? m : 0.f);
            const float e5 = row[(q < 13) ? 4 : 3] * ((q < 13) ? m : 0.f);
            r[dh][0] = e0;
            r[dh][1] = mid.x * m; r[dh][2] = mid.y * m;
            r[dh][3] = mid.z * m; r[dh][4] = mid.w * m;
            r[dh][5] = e5;
        }
    };

    float bufA[3][6], bufB[3][6];
    loadrows(c0, bufA);                    // prologue load in flight during staging

    // stage weights to LDS (2304 floats, 18/thread, coalesced)
#pragma unroll
    for (int i = 0; i < 18; ++i) smem[threadIdx.x + i * 128] = wpk[threadIdx.x + i * 128];
    __syncthreads();

    float acc[4][4];
#pragma unroll
    for (int hd = 0; hd < 4; ++hd)
#pragma unroll
        for (int j = 0; j < 4; ++j) acc[hd][j] = 0.f;

#pragma unroll
    for (int i = 0; i < 8; ++i) {
        float (*cur)[6] = (i & 1) ? bufB : bufA;
        float (*nxt)[6] = (i & 1) ? bufA : bufB;
        if (i < 7) loadrows(c0 + i + 1, nxt);   // prefetch next channel

        const int c = c0 + i;
#pragma unroll
        for (int dh = 0; dh < 3; ++dh) {
            const float* wb = &smem[c * 36 + dh * 12];
            const float4 wk0 = *(const float4*)(wb);
            const float4 wk1 = *(const float4*)(wb + 4);
            const float4 wk2 = *(const float4*)(wb + 8);
#pragma unroll
            for (int j = 0; j < 4; ++j) {
                const float a0 = cur[dh][j], a1 = cur[dh][j + 1], a2 = cur[dh][j + 2];
                acc[0][j] = fmaf(a0, wk0.x, fmaf(a1, wk1.x, fmaf(a2, wk2.x, acc[0][j])));
                acc[1][j] = fmaf(a0, wk0.y, fmaf(a1, wk1.y, fmaf(a2, wk2.y, acc[1][j])));
                acc[2][j] = fmaf(a0, wk0.z, fmaf(a1, wk1.z, fmaf(a2, wk2.z, acc[2][j])));
                acc[3][j] = fmaf(a0, wk0.w, fmaf(a1, wk1.w, fmaf(a2, wk2.w, acc[3][j])));
            }
        }
    }

    // weights dead; re-barrier before overwriting smem with reduce scratch
    __syncthreads();

    // chunk-reduce attn accumulators through LDS
    float* mine = &l[chunk][qi][0];
#pragma unroll
    for (int hd = 0; hd < 4; ++hd)
#pragma unroll
        for (int j = 0; j < 4; ++j) mine[hd * 4 + j] = acc[hd][j];
    __syncthreads();

    if (threadIdx.x < 64) {
        const int hd = threadIdx.x >> 4;
        const int rq = threadIdx.x & 15;
        float s0 = ab[hd], s1 = s0, s2 = s0, s3 = s0;
#pragma unroll
        for (int cch = 0; cch < 8; ++cch) {
            const float* p = &l[cch][rq][hd * 4];
            s0 += p[0]; s1 += p[1]; s2 += p[2]; s3 += p[3];
        }
        float4 o;
        o.x = s0 > 0.f ? 1.f / (1.f + __expf(-s0)) : 0.5f;
        o.y = s1 > 0.f ? 1.f / (1.f + __expf(-s1)) : 0.5f;
        o.z = s2 > 0.f ? 1.f / (1.f + __expf(-s2)) : 0.5f;
        o.w = s3 > 0.f ? 1.f / (1.f + __expf(-s3)) : 0.5f;
        *(float4*)(attn + (size_t)(n * 4 + hd) * HW + (tile * 16 + rq) * 4) = o;
        abuf[hd][rq] = o;
    }
    __syncthreads();

    // ---- fused stats: v = x*attn; central-row x RE-LOADED (L2-hot, bit-identical:
    // central row = xn + c*HW + quad*4, never masked) ----
    const int head = chunk >> 1;           // all 8 channels of a thread share one head
    const float4 a4 = abuf[head][qi];
    float s[8], sq[8];
#pragma unroll
    for (int i = 0; i < 8; ++i) {
        const float4 xv = *(const float4*)(xn + (size_t)(c0 + i) * HW + quad * 4);
        const float v0 = xv.x * a4.x;
        const float v1 = xv.y * a4.y;
        const float v2 = xv.z * a4.z;
        const float v3 = xv.w * a4.w;
        s[i] = v0 + v1 + v2 + v3;
        sq[i] = v0 * v0 + v1 * v1 + v2 * v2 + v3 * v3;
    }
    // per-chunk reduce over the 16 qi threads via LDS (reuse l)
#pragma unroll
    for (int i = 0; i < 8; ++i) { mine[i] = s[i]; mine[8 + i] = sq[i]; }
    __syncthreads();
    {
        const int ch2 = threadIdx.x >> 4;  // chunk being reduced
        const int k = threadIdx.x & 15;    // 0..7 = sum, 8..15 = sumsq
        float t = 0.f;
#pragma unroll
        for (int qq = 0; qq < 16; ++qq) t += l[ch2][qq][k];
        const int cc = ch2 * 8 + (k & 7);
        const int rep = blockIdx.x & 15;
        atomicAdd(&stats[rep * 128 + (k >> 3) * 64 + cc], t);
    }
}

// ---------- K4: xbnr = relu(x*attn*scale + shift) -> bf16, attn staged in LDS ----------
// Finalize FOLDED IN: each block computes scale/shift from stats (8 KB, L2-hot)
// redundantly in threads 0..63 -> k_finalize dispatch deleted. Kernel-boundary
// visibility of stats atomics makes this race-free (no device fences).
// Block = (n, spatial slab of 392 px); grid 1024 x 256.
__global__ __launch_bounds__(256) void k_xbnr(const float* __restrict__ x,
                                              const float* __restrict__ attn,
                                              const float* __restrict__ stats,
                                              const float* __restrict__ gamma,
                                              const float* __restrict__ beta,
                                              unsigned short* __restrict__ xbnr) {
    const int s = blockIdx.x & 7;          // spatial slab
    const int n = blockIdx.x >> 3;         // 0..127
    const int base_sp = s * 392;           // pixel offset

    __shared__ float al[4 * 392];          // attn slab [head][392]
    __shared__ float ssl[128];
    for (int i = threadIdx.x; i < 392; i += 256) {   // 98 float4 per head
        const int hd = i / 98;
        const int j = i - hd * 98;
        ((float4*)al)[hd * 98 + j] =
            *(const float4*)(attn + (size_t)(n * 4 + hd) * HW + base_sp + j * 4);
    }
    if (threadIdx.x < 64) {                // inline finalize
        const int c = threadIdx.x;
        float S = 0.f, Q = 0.f;
#pragma unroll
        for (int r = 0; r < 16; ++r) {
            S += stats[r * 128 + c];
            Q += stats[r * 128 + 64 + c];
        }
        const float cnt = 401408.0f;       // 128*3136
        const float mean = S / cnt;
        const float var = Q / cnt - mean * mean;
        const float scale = gamma[c] * rsqrtf(var + 1e-5f);
        ssl[c] = scale;
        ssl[64 + c] = beta[c] - mean * scale;
    }
    __syncthreads();

    for (int wi = threadIdx.x; wi < 6272; wi += 256) {
        const int c = wi / 98;
        const int j = wi - c * 98;
        const float sc = ssl[c], sh = ssl[64 + c];
        const float4 xv = *(const float4*)(x + (size_t)(n * 64 + c) * HW + base_sp + j * 4);
        const float4 av = ((const float4*)al)[(c >> 4) * 98 + j];
        ushort4 o;
        o.x = f2bf(fmaxf(fmaf(xv.x * av.x, sc, sh), 0.f));
        o.y = f2bf(fmaxf(fmaf(xv.y * av.y, sc, sh), 0.f));
        o.z = f2bf(fmaxf(fmaf(xv.z * av.z, sc, sh), 0.f));
        o.w = f2bf(fmaxf(fmaf(xv.w * av.w, sc, sh), 0.f));
        *(ushort4*)(xbnr + (size_t)(n * 64 + c) * HW + base_sp + j * 4) = o;
    }
}

// ---------- K5: grouped conv3d + bias + tanh -> gate (LDS chunk-reduction) ----------
// Round-1 structure + weights staged in LDS (pins codegen: no global loads in loop).
// Block 128 = 8 ic-chunks x 16 quads. Grid = b(16) * oc(2) * tile(49).
__global__ __launch_bounds__(128) void k_conv3d(const unsigned short* __restrict__ xbnr,
                                                const float* __restrict__ w3,
                                                const float* __restrict__ b3,
                                                float* __restrict__ gate) {
    const int tile = blockIdx.x % 49;
    const int oc = (blockIdx.x / 49) & 1;
    const int b = blockIdx.x / 98;
    const int chunk = threadIdx.x >> 4;    // 0..7
    const int qi = threadIdx.x & 15;       // 0..15
    const int quad = tile * 16 + qi;       // 0..783
    const int q = quad % 14;
    const int h = quad / 14;
    const int w0 = q * 4;

    __shared__ float wlds[864];            // this oc's 32 ic x 27 weights
    for (int i = threadIdx.x; i < 864; i += 128) wlds[i] = w3[oc * 864 + i];
    __syncthreads();

    float acc[8][4];
#pragma unroll
    for (int t = 0; t < 8; ++t)
#pragma unroll
        for (int j = 0; j < 4; ++j) acc[t][j] = 0.f;

    const int ic0 = chunk * 4;
    for (int ic = ic0; ic < ic0 + 4; ++ic) {
        const int c = oc * 32 + ic;
        const unsigned short* cbase = xbnr + (size_t)(b * 8 * 64 + c) * HW;
        const float* wic = &wlds[ic * 27];  // (dt, dh, dw)
#pragma unroll
        for (int tt = 0; tt < 8; ++tt) {
            const unsigned short* plane = cbase + (size_t)tt * (64 * HW);
#pragma unroll
            for (int dh = 0; dh < 3; ++dh) {
                const int hh = h + dh - 1;
                if (hh < 0 || hh >= 56) continue;
                const unsigned short* row = plane + hh * 56 + w0;
                const ushort4 mid = *(const ushort4*)row;
                const float f0 = (q > 0) ? bf2f(row[-1]) : 0.f;
                const float f1 = bf2f(mid.x), f2 = bf2f(mid.y);
                const float f3 = bf2f(mid.z), f4 = bf2f(mid.w);
                const float f5 = (q < 13) ? bf2f(row[4]) : 0.f;
#pragma unroll
                for (int dt = 0; dt < 3; ++dt) {
                    const int t = tt + 1 - dt;   // out[t] += in[t+dt-1]*w[dt]
                    if (t < 0 || t > 7) continue;
                    const float* wp = wic + dt * 9 + dh * 3;
                    const float wa = wp[0], wb = wp[1], wc = wp[2];
                    acc[t][0] = fmaf(f0, wa, fmaf(f1, wb, fmaf(f2, wc, acc[t][0])));
                    acc[t][1] = fmaf(f1, wa, fmaf(f2, wb, fmaf(f3, wc, acc[t][1])));
                    acc[t][2] = fmaf(f2, wa, fmaf(f3, wb, fmaf(f4, wc, acc[t][2])));
                    acc[t][3] = fmaf(f3, wa, fmaf(f4, wb, fmaf(f5, wc, acc[t][3])));
                }
            }
        }
    }

    // LDS reduction over chunks. Layout: [chunk][qi][9 float4] (pad 8->9 breaks bank alias)
    __shared__ float4 l4[8 * 16 * 9];
    float4* mine = &l4[(chunk * 16 + qi) * 9];
#pragma unroll
    for (int t = 0; t < 8; ++t) {
        float4 v;
        v.x = acc[t][0]; v.y = acc[t][1]; v.z = acc[t][2]; v.w = acc[t][3];
        mine[t] = v;
    }
    __syncthreads();

    const int rt = threadIdx.x >> 4;   // t of this thread's output
    const int rq = threadIdx.x & 15;   // quad within tile
    float4 s = l4[(0 * 16 + rq) * 9 + rt];
#pragma unroll
    for (int c = 1; c < 8; ++c) {
        const float4 v = l4[(c * 16 + rq) * 9 + rt];
        s.x += v.x; s.y += v.y; s.z += v.z; s.w += v.w;
    }
    const float bb = b3[oc];
    float4 o;
    o.x = tanhf(s.x + bb);
    o.y = tanhf(s.y + bb);
    o.z = tanhf(s.z + bb);
    o.w = tanhf(s.w + bb);
    const int outquad = tile * 16 + rq;
    *(float4*)(gate + (size_t)((b * 2 + oc) * 8 + rt) * HW + outquad * 4) = o;
}

// ---------- K6: final gating + temporal shift + interleave ----------
// Block = (b, h, head-pair): 448 threads = 32 co x 14 q, grid = 16*56*2 = 1792.
// All threads share grp (gate read exactly once) and two heads (attn read once;
// 16 same-address lanes coalesce to one transaction). FETCH ideal ~117 MB.
__global__ __launch_bounds__(448) void k_final(const float* __restrict__ x,
                                               const float* __restrict__ attn,
                                               const float* __restrict__ gate,
                                               float* __restrict__ out) {
    const int hg = blockIdx.x & 1;          // head-pair group == grp
    const int h = (blockIdx.x >> 1) % 56;
    const int b = blockIdx.x / 112;
    const int q = threadIdx.x % 14;
    const int col = threadIdx.x / 14;       // 0..31
    const int co = hg * 32 + col;
    const int sp = h * 56 + q * 4;

    int cs;
    if (co < 32) {
        cs = ((co & 1) << 4) | (co >> 1);
    } else {
        const int cc = co - 32;
        cs = 32 + (((cc & 1) << 4) | (cc >> 1));
    }
    const int grp = hg;
    const int head = cs >> 4;

    float4 x2v[8], g[8];
#pragma unroll
    for (int t = 0; t < 8; ++t) {
        const int n = b * 8 + t;
        const float4 xv = *(const float4*)(x + (size_t)(n * 64 + cs) * HW + sp);
        const float4 av = *(const float4*)(attn + (size_t)(n * 4 + head) * HW + sp);
        const float4 gv = *(const float4*)(gate + (size_t)((b * 2 + grp) * 8 + t) * HW + sp);
        x2v[t].x = xv.x * av.x;
        x2v[t].y = xv.y * av.y;
        x2v[t].z = xv.z * av.z;
        x2v[t].w = xv.w * av.w;
        g[t] = gv;
    }
#pragma unroll
    for (int t = 0; t < 8; ++t) {
        float4 o;
        o.x = x2v[t].x * (1.f - g[t].x);
        o.y = x2v[t].y * (1.f - g[t].y);
        o.z = x2v[t].z * (1.f - g[t].z);
        o.w = x2v[t].w * (1.f - g[t].w);
        if (grp == 0) {
            if (t < 7) {
                o.x += x2v[t + 1].x * g[t + 1].x;
                o.y += x2v[t + 1].y * g[t + 1].y;
                o.z += x2v[t + 1].z * g[t + 1].z;
                o.w += x2v[t + 1].w * g[t + 1].w;
            }
        } else {
            if (t > 0) {
                o.x += x2v[t - 1].x * g[t - 1].x;
                o.y += x2v[t - 1].y * g[t - 1].y;
                o.z += x2v[t - 1].z * g[t - 1].z;
                o.w += x2v[t - 1].w * g[t - 1].w;
            }
        }
        *(float4*)(out + (size_t)((b * 8 + t) * 64 + co) * HW + sp) = o;
    }
}

// ---------- launch ----------
extern "C" void kernel_launch(void* const* d_in, const int* in_sizes, int n_in,
                              void* d_out, int out_size, void* d_ws, size_t ws_size,
                              hipStream_t stream) {
    const float* x = (const float*)d_in[0];
    const float* aw = (const float*)d_in[1];
    const float* ab = (const float*)d_in[2];
    const float* gamma = (const float*)d_in[3];
    const float* beta = (const float*)d_in[4];
    const float* w3 = (const float*)d_in[5];
    const float* b3 = (const float*)d_in[6];
    float* out = (float*)d_out;

    char* ws = (char*)d_ws;
    // layout: xbnr bf16 [0, 51380224) | attn f32 | gate f32 (stats aliases its head,
    // lifetimes disjoint: stats dead before k_conv3d writes gate) | wpk
    unsigned short* xbnr = (unsigned short*)ws;
    float* attn = (float*)(ws + 51380224);            // 128*4*3136 f32 = 6422528 B
    float* gate = (float*)(ws + 57802752);            // 16*2*8*3136 f32 = 3211264 B
    float* stats = (float*)(ws + 57802752);           // 16 reps x 128 f32 = 8192 B (aliases gate)
    float* wpk = (float*)(ws + 61015040);             // 2304 f32

    k_repack<<<9, 256, 0, stream>>>(aw, wpk, stats);  // also zeroes stats
    k_attn<<<6272, 128, 0, stream>>>(x, wpk, ab, attn, stats);
    k_xbnr<<<1024, 256, 0, stream>>>(x, attn, stats, gamma, beta, xbnr);
    k_conv3d<<<1568, 128, 0, stream>>>(xbnr, w3, b3, gate);
    k_final<<<1792, 448, 0, stream>>>(x, attn, gate, out);
}

// Round 11
// 344.781 us; speedup vs baseline: 1.2756x; 1.0464x over previous
//
#include <hip/hip_runtime.h>
#include <hip/hip_bf16.h>

#define HW 3136      // 56*56
#define CTOT 64
#define NTOT 128
#define BB 16
#define TTT 8

// ---------- helpers ----------
static __device__ __forceinline__ float bf2f(unsigned short u) {
    union { unsigned int ui; float f; } v;
    v.ui = ((unsigned int)u) << 16;
    return v.f;
}
static __device__ __forceinline__ unsigned short f2bf(float f) {
    union { float f; unsigned int u; } v;
    v.f = f;
    unsigned int u = v.u;
    unsigned int r = (u + 0x7fffu + ((u >> 16) & 1u)) >> 16;  // round-nearest-even
    return (unsigned short)r;
}

// ---------- K0: repack attn weights to [c][dh][kw][head] + zero stats ----------
// grid 9 x 256 = 2304 exact; idx<2048 also zeroes the stats replicas (memset fused).
__global__ void k_repack(const float* __restrict__ aw, float* __restrict__ wpk,
                         float* __restrict__ stats) {
    const int idx = blockIdx.x * 256 + threadIdx.x;  // 2304 exact
    if (idx < 2048) stats[idx] = 0.f;
    if (idx >= 2304) return;
    const int hd = idx & 3;
    const int kw = (idx >> 2) % 3;
    const int dh = (idx / 12) % 3;
    const int c = idx / 36;
    wpk[idx] = aw[hd * 576 + c * 9 + dh * 3 + kw];
}

// ---------- K1: attn = sigmoid(relu(conv2d(x))) FUSED with per-channel stats ----------
// r10 version (VGPR 56, no spill, 82us): stats phase re-loads central-row x (L2-hot,
// bit-identical). No launch_bounds waves-hint (r8/r9: any hint -> forced spill).
// LDS aliased: wl/l share smem -> 10240 B.
// Block 128 = 8 chunks(8ch) x 16 quads; grid = n(128) * tile(49).
__global__ __launch_bounds__(128) void k_attn(const float* __restrict__ x,
                                              const float* __restrict__ wpk,
                                              const float* __restrict__ ab,
                                              float* __restrict__ attn,
                                              float* __restrict__ stats) {
    const int tile = blockIdx.x % 49;
    const int n = blockIdx.x / 49;
    const int chunk = threadIdx.x >> 4;    // 0..7
    const int qi = threadIdx.x & 15;       // 0..15
    const int quad = tile * 16 + qi;       // 0..783
    const int q = quad % 14;
    const int h = quad / 14;
    const int w0 = q * 4;

    __shared__ float smem[2304];           // phase A: weights; phase B: reduce scratch
    __shared__ float4 abuf[4][16];         // attn broadcast [head][quad-in-tile]
    float (*l)[16][17] = (float (*)[16][17])smem;

    const float* xn = x + (size_t)n * CTOT * HW;
    const int c0 = chunk * 8;

    // branchless row loader: clamped address + validity mask, address-select edges
    auto loadrows = [&](int c, float r[3][6]) {
#pragma unroll
        for (int dh = 0; dh < 3; ++dh) {
            const int hh = h + dh - 1;
            const bool v = (hh >= 0) && (hh < 56);
            const float* row = xn + c * HW + (v ? hh : h) * 56 + w0;
            const float m = v ? 1.f : 0.f;
            const float4 mid = *(const float4*)row;
            const float e0 = row[(q > 0) ? -1 : 0] * ((q > 0) ? m : 0.f);
            const float e5 = row[(q < 13) ? 4 : 3] * ((q < 13) ? m : 0.f);
            r[dh][0] = e0;
            r[dh][1] = mid.x * m; r[dh][2] = mid.y * m;
            r[dh][3] = mid.z * m; r[dh][4] = mid.w * m;
            r[dh][5] = e5;
        }
    };

    float bufA[3][6], bufB[3][6];
    loadrows(c0, bufA);                    // prologue load in flight during staging

    // stage weights to LDS (2304 floats, 18/thread, coalesced)
#pragma unroll
    for (int i = 0; i < 18; ++i) smem[threadIdx.x + i * 128] = wpk[threadIdx.x + i * 128];
    __syncthreads();

    float acc[4][4];
#pragma unroll
    for (int hd = 0; hd < 4; ++hd)
#pragma unroll
        for (int j = 0; j < 4; ++j) acc[hd][j] = 0.f;

#pragma unroll
    for (int i = 0; i < 8; ++i) {
        float (*cur)[6] = (i & 1) ? bufB : bufA;
        float (*nxt)[6] = (i & 1) ? bufA : bufB;
        if (i < 7) loadrows(c0 + i + 1, nxt);   // prefetch next channel

        const int c = c0 + i;
#pragma unroll
        for (int dh = 0; dh < 3; ++dh) {
            const float* wb = &smem[c * 36 + dh * 12];
            const float4 wk0 = *(const float4*)(wb);
            const float4 wk1 = *(const float4*)(wb + 4);
            const float4 wk2 = *(const float4*)(wb + 8);
#pragma unroll
            for (int j = 0; j < 4; ++j) {
                const float a0 = cur[dh][j], a1 = cur[dh][j + 1], a2 = cur[dh][j + 2];
                acc[0][j] = fmaf(a0, wk0.x, fmaf(a1, wk1.x, fmaf(a2, wk2.x, acc[0][j])));
                acc[1][j] = fmaf(a0, wk0.y, fmaf(a1, wk1.y, fmaf(a2, wk2.y, acc[1][j])));
                acc[2][j] = fmaf(a0, wk0.z, fmaf(a1, wk1.z, fmaf(a2, wk2.z, acc[2][j])));
                acc[3][j] = fmaf(a0, wk0.w, fmaf(a1, wk1.w, fmaf(a2, wk2.w, acc[3][j])));
            }
        }
    }

    // weights dead; re-barrier before overwriting smem with reduce scratch
    __syncthreads();

    // chunk-reduce attn accumulators through LDS
    float* mine = &l[chunk][qi][0];
#pragma unroll
    for (int hd = 0; hd < 4; ++hd)
#pragma unroll
        for (int j = 0; j < 4; ++j) mine[hd * 4 + j] = acc[hd][j];
    __syncthreads();

    if (threadIdx.x < 64) {
        const int hd = threadIdx.x >> 4;
        const int rq = threadIdx.x & 15;
        float s0 = ab[hd], s1 = s0, s2 = s0, s3 = s0;
#pragma unroll
        for (int cch = 0; cch < 8; ++cch) {
            const float* p = &l[cch][rq][hd * 4];
            s0 += p[0]; s1 += p[1]; s2 += p[2]; s3 += p[3];
        }
        float4 o;
        o.x = s0 > 0.f ? 1.f / (1.f + __expf(-s0)) : 0.5f;
        o.y = s1 > 0.f ? 1.f / (1.f + __expf(-s1)) : 0.5f;
        o.z = s2 > 0.f ? 1.f / (1.f + __expf(-s2)) : 0.5f;
        o.w = s3 > 0.f ? 1.f / (1.f + __expf(-s3)) : 0.5f;
        *(float4*)(attn + (size_t)(n * 4 + hd) * HW + (tile * 16 + rq) * 4) = o;
        abuf[hd][rq] = o;
    }
    __syncthreads();

    // ---- fused stats: v = x*attn; central-row x re-loaded (L2-hot, bit-identical) ----
    const int head = chunk >> 1;           // all 8 channels of a thread share one head
    const float4 a4 = abuf[head][qi];
    float s[8], sq[8];
#pragma unroll
    for (int i = 0; i < 8; ++i) {
        const float4 xv = *(const float4*)(xn + (size_t)(c0 + i) * HW + quad * 4);
        const float v0 = xv.x * a4.x;
        const float v1 = xv.y * a4.y;
        const float v2 = xv.z * a4.z;
        const float v3 = xv.w * a4.w;
        s[i] = v0 + v1 + v2 + v3;
        sq[i] = v0 * v0 + v1 * v1 + v2 * v2 + v3 * v3;
    }
    // per-chunk reduce over the 16 qi threads via LDS (reuse l)
#pragma unroll
    for (int i = 0; i < 8; ++i) { mine[i] = s[i]; mine[8 + i] = sq[i]; }
    __syncthreads();
    {
        const int ch2 = threadIdx.x >> 4;  // chunk being reduced
        const int k = threadIdx.x & 15;    // 0..7 = sum, 8..15 = sumsq
        float t = 0.f;
#pragma unroll
        for (int qq = 0; qq < 16; ++qq) t += l[ch2][qq][k];
        const int cc = ch2 * 8 + (k & 7);
        const int rep = blockIdx.x & 15;
        atomicAdd(&stats[rep * 128 + (k >> 3) * 64 + cc], t);
    }
}

// ---------- K4: xbnr = relu(x*attn*scale + shift) -> bf16, attn staged in LDS ----------
// Finalize folded in (threads 0..63 compute scale/shift from L2-hot stats).
// Block = (n, spatial slab of 392 px); grid 1024 x 256.
__global__ __launch_bounds__(256) void k_xbnr(const float* __restrict__ x,
                                              const float* __restrict__ attn,
                                              const float* __restrict__ stats,
                                              const float* __restrict__ gamma,
                                              const float* __restrict__ beta,
                                              unsigned short* __restrict__ xbnr) {
    const int s = blockIdx.x & 7;          // spatial slab
    const int n = blockIdx.x >> 3;         // 0..127
    const int base_sp = s * 392;           // pixel offset

    __shared__ float al[4 * 392];          // attn slab [head][392]
    __shared__ float ssl[128];
    for (int i = threadIdx.x; i < 392; i += 256) {   // 98 float4 per head
        const int hd = i / 98;
        const int j = i - hd * 98;
        ((float4*)al)[hd * 98 + j] =
            *(const float4*)(attn + (size_t)(n * 4 + hd) * HW + base_sp + j * 4);
    }
    if (threadIdx.x < 64) {                // inline finalize
        const int c = threadIdx.x;
        float S = 0.f, Q = 0.f;
#pragma unroll
        for (int r = 0; r < 16; ++r) {
            S += stats[r * 128 + c];
            Q += stats[r * 128 + 64 + c];
        }
        const float cnt = 401408.0f;       // 128*3136
        const float mean = S / cnt;
        const float var = Q / cnt - mean * mean;
        const float scale = gamma[c] * rsqrtf(var + 1e-5f);
        ssl[c] = scale;
        ssl[64 + c] = beta[c] - mean * scale;
    }
    __syncthreads();

    for (int wi = threadIdx.x; wi < 6272; wi += 256) {
        const int c = wi / 98;
        const int j = wi - c * 98;
        const float sc = ssl[c], sh = ssl[64 + c];
        const float4 xv = *(const float4*)(x + (size_t)(n * 64 + c) * HW + base_sp + j * 4);
        const float4 av = ((const float4*)al)[(c >> 4) * 98 + j];
        ushort4 o;
        o.x = f2bf(fmaxf(fmaf(xv.x * av.x, sc, sh), 0.f));
        o.y = f2bf(fmaxf(fmaf(xv.y * av.y, sc, sh), 0.f));
        o.z = f2bf(fmaxf(fmaf(xv.z * av.z, sc, sh), 0.f));
        o.w = f2bf(fmaxf(fmaf(xv.w * av.w, sc, sh), 0.f));
        *(ushort4*)(xbnr + (size_t)(n * 64 + c) * HW + base_sp + j * 4) = o;
    }
}

// ---------- K5: MERGED conv3d+tanh gate AND final gating/shift/interleave ----------
// Conv phase byte-identical to the proven k_conv3d (wlds LDS weights, branchy rows,
// l4 chunk-reduce). Gate goes to LDS (gl aliases dead wlds -> LDS unchanged), NOT
// HBM: kills the gate round-trip + one dispatch. Final phase streams
// out[t] = x2[t] - y[t] + y[t -/+ 1] with a 1-register y pipeline (grp0: +y[t+1],
// grp1: +y[t-1]), channel map identical to the validated k_final.
// Block 128 = 8 ic-chunks x 16 quads. Grid = b(16) * oc(2) * tile(49).
__global__ __launch_bounds__(128) void k_gate(const unsigned short* __restrict__ xbnr,
                                              const float* __restrict__ w3,
                                              const float* __restrict__ b3,
                                              const float* __restrict__ x,
                                              const float* __restrict__ attn,
                                              float* __restrict__ out) {
    const int tile = blockIdx.x % 49;
    const int oc = (blockIdx.x / 49) & 1;
    const int b = blockIdx.x / 98;
    const int chunk = threadIdx.x >> 4;    // 0..7
    const int qi = threadIdx.x & 15;       // 0..15
    const int quad = tile * 16 + qi;       // 0..783
    const int q = quad % 14;
    const int h = quad / 14;
    const int w0 = q * 4;

    __shared__ float wlds[864];            // phase A: weights; phase C: gate gl[8][16] f4 (512 f)
    float4* gl = (float4*)wlds;
    for (int i = threadIdx.x; i < 864; i += 128) wlds[i] = w3[oc * 864 + i];
    __syncthreads();

    float acc[8][4];
#pragma unroll
    for (int t = 0; t < 8; ++t)
#pragma unroll
        for (int j = 0; j < 4; ++j) acc[t][j] = 0.f;

    const int ic0 = chunk * 4;
    for (int ic = ic0; ic < ic0 + 4; ++ic) {
        const int c = oc * 32 + ic;
        const unsigned short* cbase = xbnr + (size_t)(b * 8 * 64 + c) * HW;
        const float* wic = &wlds[ic * 27];  // (dt, dh, dw)
#pragma unroll
        for (int tt = 0; tt < 8; ++tt) {
            const unsigned short* plane = cbase + (size_t)tt * (64 * HW);
#pragma unroll
            for (int dh = 0; dh < 3; ++dh) {
                const int hh = h + dh - 1;
                if (hh < 0 || hh >= 56) continue;
                const unsigned short* row = plane + hh * 56 + w0;
                const ushort4 mid = *(const ushort4*)row;
                const float f0 = (q > 0) ? bf2f(row[-1]) : 0.f;
                const float f1 = bf2f(mid.x), f2 = bf2f(mid.y);
                const float f3 = bf2f(mid.z), f4 = bf2f(mid.w);
                const float f5 = (q < 13) ? bf2f(row[4]) : 0.f;
#pragma unroll
                for (int dt = 0; dt < 3; ++dt) {
                    const int t = tt + 1 - dt;   // out[t] += in[t+dt-1]*w[dt]
                    if (t < 0 || t > 7) continue;
                    const float* wp = wic + dt * 9 + dh * 3;
                    const float wa = wp[0], wb = wp[1], wc = wp[2];
                    acc[t][0] = fmaf(f0, wa, fmaf(f1, wb, fmaf(f2, wc, acc[t][0])));
                    acc[t][1] = fmaf(f1, wa, fmaf(f2, wb, fmaf(f3, wc, acc[t][1])));
                    acc[t][2] = fmaf(f2, wa, fmaf(f3, wb, fmaf(f4, wc, acc[t][2])));
                    acc[t][3] = fmaf(f3, wa, fmaf(f4, wb, fmaf(f5, wc, acc[t][3])));
                }
            }
        }
    }

    // LDS reduction over chunks. Layout: [chunk][qi][9 float4] (pad 8->9 breaks bank alias)
    __shared__ float4 l4[8 * 16 * 9];
    float4* mine = &l4[(chunk * 16 + qi) * 9];
#pragma unroll
    for (int t = 0; t < 8; ++t) {
        float4 v;
        v.x = acc[t][0]; v.y = acc[t][1]; v.z = acc[t][2]; v.w = acc[t][3];
        mine[t] = v;
    }
    __syncthreads();   // also: all wlds reads done -> gl may overwrite it

    {
        const int rt = threadIdx.x >> 4;   // t of this thread's gate
        const int rq = threadIdx.x & 15;   // quad within tile
        float4 s = l4[(0 * 16 + rq) * 9 + rt];
#pragma unroll
        for (int c = 1; c < 8; ++c) {
            const float4 v = l4[(c * 16 + rq) * 9 + rt];
            s.x += v.x; s.y += v.y; s.z += v.z; s.w += v.w;
        }
        const float bb = b3[oc];
        float4 o;
        o.x = tanhf(s.x + bb);
        o.y = tanhf(s.y + bb);
        o.z = tanhf(s.z + bb);
        o.w = tanhf(s.w + bb);
        gl[rt * 16 + rq] = o;              // gate -> LDS only (no HBM round-trip)
    }
    __syncthreads();

    // ---- final phase: out[t] = x2[t] - y[t] + y[t-/+1], y = x2*gate ----
    const int grp = oc;
#pragma unroll
    for (int k = 0; k < 4; ++k) {
        const int cell = threadIdx.x + k * 128;   // 0..511 = 32 co x 16 qq
        const int co = cell >> 4;                 // 0..31 (within group)
        const int qq = cell & 15;
        const int sp = (tile * 16 + qq) * 4;
        const int cs = grp * 32 + (((co & 1) << 4) | (co >> 1));
        const int head = cs >> 4;
        const int co_out = grp * 32 + co;

        float4 yc; yc.x = 0.f; yc.y = 0.f; yc.z = 0.f; yc.w = 0.f;  // y[t+1] (grp0) / y[t-1] (grp1)
        if (grp == 0) {
            for (int t = 7; t >= 0; --t) {
                const int n = b * 8 + t;
                const float4 xv = *(const float4*)(x + (size_t)(n * 64 + cs) * HW + sp);
                const float4 av = *(const float4*)(attn + (size_t)(n * 4 + head) * HW + sp);
                const float4 g = gl[t * 16 + qq];
                float4 x2, y, o2;
                x2.x = xv.x * av.x; x2.y = xv.y * av.y; x2.z = xv.z * av.z; x2.w = xv.w * av.w;
                y.x = x2.x * g.x;   y.y = x2.y * g.y;   y.z = x2.z * g.z;   y.w = x2.w * g.w;
                o2.x = x2.x - y.x + yc.x; o2.y = x2.y - y.y + yc.y;
                o2.z = x2.z - y.z + yc.z; o2.w = x2.w - y.w + yc.w;
                yc = y;
                *(float4*)(out + (size_t)(n * 64 + co_out) * HW + sp) = o2;
            }
        } else {
            for (int t = 0; t < 8; ++t) {
                const int n = b * 8 + t;
                const float4 xv = *(const float4*)(x + (size_t)(n * 64 + cs) * HW + sp);
                const float4 av = *(const float4*)(attn + (size_t)(n * 4 + head) * HW + sp);
                const float4 g = gl[t * 16 + qq];
                float4 x2, y, o2;
                x2.x = xv.x * av.x; x2.y = xv.y * av.y; x2.z = xv.z * av.z; x2.w = xv.w * av.w;
                y.x = x2.x * g.x;   y.y = x2.y * g.y;   y.z = x2.z * g.z;   y.w = x2.w * g.w;
                o2.x = x2.x - y.x + yc.x; o2.y = x2.y - y.y + yc.y;
                o2.z = x2.z - y.z + yc.z; o2.w = x2.w - y.w + yc.w;
                yc = y;
                *(float4*)(out + (size_t)(n * 64 + co_out) * HW + sp) = o2;
            }
        }
    }
}

// ---------- launch ----------
extern "C" void kernel_launch(void* const* d_in, const int* in_sizes, int n_in,
                              void* d_out, int out_size, void* d_ws, size_t ws_size,
                              hipStream_t stream) {
    const float* x = (const float*)d_in[0];
    const float* aw = (const float*)d_in[1];
    const float* ab = (const float*)d_in[2];
    const float* gamma = (const float*)d_in[3];
    const float* beta = (const float*)d_in[4];
    const float* w3 = (const float*)d_in[5];
    const float* b3 = (const float*)d_in[6];
    float* out = (float*)d_out;

    char* ws = (char*)d_ws;
    // layout: xbnr bf16 [0, 51380224) | attn f32 | stats | wpk   (gate buffer deleted)
    unsigned short* xbnr = (unsigned short*)ws;
    float* attn = (float*)(ws + 51380224);            // 128*4*3136 f32 = 6422528 B
    float* stats = (float*)(ws + 57802752);           // 16 reps x 128 f32 = 8192 B
    float* wpk = (float*)(ws + 61015040);             // 2304 f32

    k_repack<<<9, 256, 0, stream>>>(aw, wpk, stats);  // also zeroes stats
    k_attn<<<6272, 128, 0, stream>>>(x, wpk, ab, attn, stats);
    k_xbnr<<<1024, 256, 0, stream>>>(x, attn, stats, gamma, beta, xbnr);
    k_gate<<<1568, 128, 0, stream>>>(xbnr, w3, b3, x, attn, out);
}